// Round 2
// baseline (143.292 us; speedup 1.0000x reference)
//
#include <hip/hip_runtime.h>
#include <hip/hip_bf16.h>
#include <cstddef>

// ---------------------------------------------------------------------------
// GAT 2-layer fused implementation for MI355X (gfx950).
// Key algebra: e2[edge,:] = e[edge,0:7] @ (sum_{h1,h2} att1*att2 * Mcat[h1,h2])
// with Mcat = (1/H^2) We1@We2 precomputed; s_edge via 7-dim dots; scores via
// f32 projection vectors q = W @ a. Only Wh/att go through bf16 MFMA.
// ---------------------------------------------------------------------------

typedef __attribute__((ext_vector_type(8))) short bf16x8;
typedef __attribute__((ext_vector_type(4))) short bf16x4;
typedef __attribute__((ext_vector_type(4))) float f32x4;

#define DEVINL static __device__ __forceinline__

DEVINL unsigned short f2bf(float f) {
    union { float f; unsigned u; } v; v.f = f;
    return (unsigned short)((v.u + 0x7FFFu + ((v.u >> 16) & 1u)) >> 16); // RNE
}
DEVINL float bf2f(unsigned short b) {
    union { unsigned u; float f; } v; v.u = ((unsigned)b) << 16; return v.f;
}

// ---------------- P0a: transpose W [h][f][o] f32 -> WT [h][o][f] bf16 -------
__global__ __launch_bounds__(256) void transpose_w(const float* __restrict__ W,
                                                   unsigned short* __restrict__ WT) {
    __shared__ unsigned short tile[64][65];
    const int ft = blockIdx.x * 64, ot = blockIdx.y * 64, h = blockIdx.z;
    const int t = threadIdx.x;
    const float* Wh = W + (size_t)h * 768 * 768;
    unsigned short* WTh = WT + (size_t)h * 768 * 768;
#pragma unroll
    for (int i = 0; i < 16; i++) {
        int idx = t + i * 256, r = idx >> 6, c = idx & 63;
        tile[c][r] = f2bf(Wh[(ft + r) * 768 + ot + c]);
    }
    __syncthreads();
#pragma unroll
    for (int i = 0; i < 16; i++) {
        int idx = t + i * 256, r = idx >> 6, c = idx & 63;
        WTh[(ot + r) * 768 + ft + c] = tile[r][c];
    }
}

// ---------------- P0b: f32 -> bf16 convert (vectorized x4) ------------------
__global__ __launch_bounds__(256) void cvt_bf16(const float* __restrict__ in,
                                                unsigned short* __restrict__ out, int n) {
    int i = (blockIdx.x * 256 + threadIdx.x) * 4;
    if (i >= n) return;
    float4 v = *(const float4*)&in[i];
    unsigned short pk[4] = {f2bf(v.x), f2bf(v.y), f2bf(v.z), f2bf(v.w)};
    *(bf16x4*)&out[i] = *(bf16x4*)pk;
}

// ---------------- P1: precompute q vectors, u1, Mcat ------------------------
// q[vec][h][768]: vec 0=q1s 1=q1d 2=q2s 3=q2d ; u1[2][8]; Mcat[32][384]
// Mcat row rk: hh=rk>>3 (h1=hh>>1,h2=hh&1), kk=rk&7 (kk==7 -> zero row)
__global__ __launch_bounds__(256) void precompute(
    const float* __restrict__ W1, const float* __restrict__ W2,
    const float* __restrict__ We1, const float* __restrict__ We2,
    const float* __restrict__ a1s, const float* __restrict__ a1d,
    const float* __restrict__ a1e, const float* __restrict__ a2s,
    const float* __restrict__ a2d, const float* __restrict__ a2e,
    float* __restrict__ q, float* __restrict__ u1, float* __restrict__ Mcat) {
    const int g = blockIdx.x * 32 + (threadIdx.x >> 3);
    const int lane = threadIdx.x & 7;
    float acc = 0.0f;
    if (g < 6144) {
        int vec = g / 1536, rem = g % 1536, h = rem / 768, f = rem % 768;
        const float* W = (vec < 2) ? W1 : W2;
        const float* a = (vec == 0) ? a1s : (vec == 1) ? a1d : (vec == 2) ? a2s : a2d;
        const float* wr = W + (size_t)(h * 768 + f) * 768;
        const float* ar = a + h * 768;
        for (int o = lane; o < 768; o += 8) acc += wr[o] * ar[o];
        for (int s = 4; s; s >>= 1) acc += __shfl_down(acc, s, 8);
        if (lane == 0) q[g] = acc;
    } else if (g < 6160) {
        int g2 = g - 6144, h = g2 >> 3, k = g2 & 7;
        if (k < 7) {
            const float* wr = We1 + (h * 7 + k) * 384;
            const float* ar = a1e + h * 384;
            for (int o = lane; o < 384; o += 8) acc += wr[o] * ar[o];
        }
        for (int s = 4; s; s >>= 1) acc += __shfl_down(acc, s, 8);
        if (lane == 0) u1[g2] = acc;
    } else if (g < 18448) {
        int g3 = g - 6160, rk = g3 / 384, tc = g3 % 384;
        int hh = rk >> 3, kk = rk & 7, h1 = hh >> 1, h2 = hh & 1;
        if (kk < 7) {
            const float* wr = We1 + (h1 * 7 + kk) * 384;
            const float* w2c = We2 + (size_t)h2 * 384 * 384 + tc;
            for (int o = lane; o < 384; o += 8) acc += wr[o] * w2c[o * 384];
            acc *= 0.25f; // 1/H^2
        }
        for (int s = 4; s; s >>= 1) acc += __shfl_down(acc, s, 8);
        if (lane == 0) Mcat[g3] = acc;
    }
}

// ---------------- P2: w[h1][h2][8] and Bfrag[24][64][8] from Mcat -----------
__global__ __launch_bounds__(64) void finalize_pre(const float* __restrict__ Mcat,
                                                   const float* __restrict__ a2e,
                                                   float* __restrict__ w,
                                                   unsigned short* __restrict__ Bfrag) {
    const int l = threadIdx.x;
    if (l < 32) {
        int hh = l >> 3, k = l & 7, h2 = hh & 1;
        float acc = 0.0f;
        if (k < 7)
            for (int t = 0; t < 384; t++) acc += Mcat[(hh * 8 + k) * 384 + t] * a2e[h2 * 384 + t];
        w[l] = 2.0f * acc; // * H  (Mcat has 1/H^2, s_edge2 needs 1/H)
    }
    // B fragments for mfma_f32_16x16x32_bf16: lane l holds B[(l>>4)*8+j][col=l&15]
    for (int ct = 0; ct < 24; ct++) {
        unsigned short pk[8];
#pragma unroll
        for (int j = 0; j < 8; j++)
            pk[j] = f2bf(Mcat[((l >> 4) * 8 + j) * 384 + ct * 16 + (l & 15)]);
        *(bf16x8*)&Bfrag[(ct * 64 + l) * 8] = *(bf16x8*)pk;
    }
}

// ---------------- P3/P7: s_src/s_dst dots (f32) -----------------------------
// out layout [b][h][256]
__global__ __launch_bounds__(256) void sdots(const float* __restrict__ x,
                                             const float* __restrict__ qs,
                                             const float* __restrict__ qd,
                                             float* __restrict__ out_s,
                                             float* __restrict__ out_d) {
    const int n = blockIdx.x, b = blockIdx.y, t = threadIdx.x;
    const float* xr = x + (size_t)(b * 256 + n) * 768;
    float a0 = 0, a1 = 0, a2 = 0, a3 = 0;
#pragma unroll
    for (int i = 0; i < 3; i++) {
        int k = i * 256 + t;
        float xv = xr[k];
        a0 += xv * qs[k];        // h=0
        a1 += xv * qs[768 + k];  // h=1
        a2 += xv * qd[k];
        a3 += xv * qd[768 + k];
    }
    __shared__ float red[1024];
    red[t] = a0; red[256 + t] = a1; red[512 + t] = a2; red[768 + t] = a3;
    __syncthreads();
    for (int s = 128; s > 0; s >>= 1) {
        if (t < s) {
            red[t] += red[t + s];
            red[256 + t] += red[256 + t + s];
            red[512 + t] += red[512 + t + s];
            red[768 + t] += red[768 + t + s];
        }
        __syncthreads();
    }
    if (t == 0) {
        out_s[(b * 2 + 0) * 256 + n] = red[0];
        out_s[(b * 2 + 1) * 256 + n] = red[256];
        out_d[(b * 2 + 0) * 256 + n] = red[512];
        out_d[(b * 2 + 1) * 256 + n] = red[768];
    }
}

// ---------------- P4: layer-1 attention softmax -> att1 bf16 ----------------
__global__ __launch_bounds__(256) void att_l1(const float* __restrict__ e,
                                              const int* __restrict__ adj,
                                              const float* __restrict__ s_s,
                                              const float* __restrict__ s_d,
                                              const float* __restrict__ u1,
                                              unsigned short* __restrict__ attb) {
    const int n = blockIdx.x, h = blockIdx.y, b = blockIdx.z, m = threadIdx.x;
    float ss = s_s[(b * 2 + h) * 256 + n];
    float sd = s_d[(b * 2 + h) * 256 + m];
    const float* ep = e + ((size_t)(b * 256 + n) * 256 + m) * 7;
    float se = 0.0f;
#pragma unroll
    for (int k = 0; k < 7; k++) se += ep[k] * u1[h * 8 + k];
    float sc = ss + sd + se;
    sc = sc > 0.0f ? sc : 0.2f * sc;             // leaky_relu
    sc = adj[(size_t)(b * 256 + n) * 256 + m] > 0 ? sc : -9e15f;
    __shared__ float red[256];
    red[m] = sc; __syncthreads();
    for (int s = 128; s > 0; s >>= 1) { if (m < s) red[m] = fmaxf(red[m], red[m + s]); __syncthreads(); }
    float mx = red[0]; __syncthreads();
    float ex = __expf(sc - mx);
    red[m] = ex; __syncthreads();
    for (int s = 128; s > 0; s >>= 1) { if (m < s) red[m] += red[m + s]; __syncthreads(); }
    float inv = 1.0f / red[0];
    attb[((size_t)(b * 2 + h) * 256 + n) * 256 + m] = f2bf(ex * inv);
}

// ---------------- P8: layer-2 attention softmax -> att2 bf16 ----------------
__global__ __launch_bounds__(256) void att_l2(const float* __restrict__ e,
                                              const int* __restrict__ adj,
                                              const float* __restrict__ s_s,
                                              const float* __restrict__ s_d,
                                              const float* __restrict__ w,
                                              const unsigned short* __restrict__ att1b,
                                              unsigned short* __restrict__ attb) {
    const int n = blockIdx.x, h = blockIdx.y, b = blockIdx.z, m = threadIdx.x;
    float ss = s_s[(b * 2 + h) * 256 + n];
    float sd = s_d[(b * 2 + h) * 256 + m];
    const float* ep = e + ((size_t)(b * 256 + n) * 256 + m) * 7;
    float se = 0.0f;
#pragma unroll
    for (int h1 = 0; h1 < 2; h1++) {
        float ew = 0.0f;
#pragma unroll
        for (int k = 0; k < 7; k++) ew += ep[k] * w[(h1 * 2 + h) * 8 + k];
        float a1 = bf2f(att1b[((size_t)(b * 2 + h1) * 256 + n) * 256 + m]);
        se += a1 * ew;
    }
    float sc = ss + sd + se;
    sc = sc > 0.0f ? sc : 0.2f * sc;
    sc = adj[(size_t)(b * 256 + n) * 256 + m] > 0 ? sc : -9e15f;
    __shared__ float red[256];
    red[m] = sc; __syncthreads();
    for (int s = 128; s > 0; s >>= 1) { if (m < s) red[m] = fmaxf(red[m], red[m + s]); __syncthreads(); }
    float mx = red[0]; __syncthreads();
    float ex = __expf(sc - mx);
    red[m] = ex; __syncthreads();
    for (int s = 128; s > 0; s >>= 1) { if (m < s) red[m] += red[m + s]; __syncthreads(); }
    float inv = 1.0f / red[0];
    attb[((size_t)(b * 2 + h) * 256 + n) * 256 + m] = f2bf(ex * inv);
}

// ---------------- P5: Wh^T = (x @ W)^T via bf16 MFMA ------------------------
// A: bf16 [512][768] rows=(b,n); BT: bf16 [2][768 o][768 f]; out WhT bf16
// [b][h][768 o][256 n]. grid (mtile=8, otile=12, h=2), 256 thr (4 waves 2x2).
__global__ __launch_bounds__(256) void gemm_xw(const unsigned short* __restrict__ A,
                                               const unsigned short* __restrict__ BT,
                                               unsigned short* __restrict__ WhT) {
    const int mt = blockIdx.x, ot = blockIdx.y, h = blockIdx.z;
    const int t = threadIdx.x, wv = t >> 6, l = t & 63;
    const int wm = wv >> 1, wn = wv & 1, lr = l & 15, lk = l >> 4;
    __shared__ unsigned short As[64][40];
    __shared__ unsigned short Bs[64][40];
    const int arow = t >> 2, acol = (t & 3) * 8;
    const unsigned short* Bh = BT + (size_t)h * 768 * 768;
    f32x4 acc[2][2];
#pragma unroll
    for (int i = 0; i < 2; i++)
#pragma unroll
        for (int j = 0; j < 2; j++) acc[i][j] = (f32x4){0, 0, 0, 0};
    for (int k0 = 0; k0 < 768; k0 += 32) {
        __syncthreads();
        *(bf16x8*)&As[arow][acol] = *(const bf16x8*)&A[(size_t)(mt * 64 + arow) * 768 + k0 + acol];
        *(bf16x8*)&Bs[arow][acol] = *(const bf16x8*)&Bh[(size_t)(ot * 64 + arow) * 768 + k0 + acol];
        __syncthreads();
        bf16x8 af[2], bfv[2];
#pragma unroll
        for (int i = 0; i < 2; i++) af[i] = *(const bf16x8*)&As[wm * 32 + i * 16 + lr][lk * 8];
#pragma unroll
        for (int j = 0; j < 2; j++) bfv[j] = *(const bf16x8*)&Bs[wn * 32 + j * 16 + lr][lk * 8];
#pragma unroll
        for (int i = 0; i < 2; i++)
#pragma unroll
            for (int j = 0; j < 2; j++)
                acc[i][j] = __builtin_amdgcn_mfma_f32_16x16x32_bf16(af[i], bfv[j], acc[i][j], 0, 0, 0);
    }
    // C mapping: row(M)= base + lk*4 + r (4 consecutive), col(o) = base + lr
#pragma unroll
    for (int i = 0; i < 2; i++)
#pragma unroll
        for (int j = 0; j < 2; j++) {
            int n0 = mt * 64 + wm * 32 + i * 16 + lk * 4;
            int og = ot * 64 + wn * 32 + j * 16 + lr;
            int b = n0 >> 8, n = n0 & 255;
            unsigned short pk[4];
#pragma unroll
            for (int r = 0; r < 4; r++) pk[r] = f2bf(acc[i][j][r]);
            *(bf16x4*)&WhT[((size_t)(b * 2 + h) * 768 + og) * 256 + n] = *(bf16x4*)pk;
        }
}

// ---------------- P6/P9: x' = 0.5*(elu(att@Wh)_h0 + elu_h1) + resid ---------
// attb [b][h][256][256] bf16; WhT [b][h][768][256] bf16 (BT layout);
// grid (mtile=4, otile=12, b=2). xbout optional bf16 copy.
__global__ __launch_bounds__(256) void gemm_att(const unsigned short* __restrict__ attb,
                                                const unsigned short* __restrict__ WhT,
                                                const float* __restrict__ resid,
                                                float* __restrict__ xout,
                                                unsigned short* __restrict__ xbout) {
    const int mt = blockIdx.x, ot = blockIdx.y, b = blockIdx.z;
    const int t = threadIdx.x, wv = t >> 6, l = t & 63;
    const int wm = wv >> 1, wn = wv & 1, lr = l & 15, lk = l >> 4;
    __shared__ unsigned short As[64][40];
    __shared__ unsigned short Bs[64][40];
    const int arow = t >> 2, acol = (t & 3) * 8;
    float res[2][2][4] = {};
    for (int h = 0; h < 2; h++) {
        const unsigned short* Ah = attb + (size_t)(b * 2 + h) * 256 * 256;
        const unsigned short* Bh = WhT + (size_t)(b * 2 + h) * 768 * 256;
        f32x4 acc[2][2];
#pragma unroll
        for (int i = 0; i < 2; i++)
#pragma unroll
            for (int j = 0; j < 2; j++) acc[i][j] = (f32x4){0, 0, 0, 0};
        for (int k0 = 0; k0 < 256; k0 += 32) {
            __syncthreads();
            *(bf16x8*)&As[arow][acol] = *(const bf16x8*)&Ah[(size_t)(mt * 64 + arow) * 256 + k0 + acol];
            *(bf16x8*)&Bs[arow][acol] = *(const bf16x8*)&Bh[(size_t)(ot * 64 + arow) * 256 + k0 + acol];
            __syncthreads();
            bf16x8 af[2], bfv[2];
#pragma unroll
            for (int i = 0; i < 2; i++) af[i] = *(const bf16x8*)&As[wm * 32 + i * 16 + lr][lk * 8];
#pragma unroll
            for (int j = 0; j < 2; j++) bfv[j] = *(const bf16x8*)&Bs[wn * 32 + j * 16 + lr][lk * 8];
#pragma unroll
            for (int i = 0; i < 2; i++)
#pragma unroll
                for (int j = 0; j < 2; j++)
                    acc[i][j] = __builtin_amdgcn_mfma_f32_16x16x32_bf16(af[i], bfv[j], acc[i][j], 0, 0, 0);
        }
#pragma unroll
        for (int i = 0; i < 2; i++)
#pragma unroll
            for (int j = 0; j < 2; j++)
#pragma unroll
                for (int r = 0; r < 4; r++) {
                    float v = acc[i][j][r];
                    res[i][j][r] += (v > 0.0f ? v : (expf(v) - 1.0f)); // elu
                }
        __syncthreads();
    }
#pragma unroll
    for (int i = 0; i < 2; i++)
#pragma unroll
        for (int j = 0; j < 2; j++) {
            int n0 = mt * 64 + wm * 32 + i * 16 + lk * 4;
            int og = ot * 64 + wn * 32 + j * 16 + lr;
#pragma unroll
            for (int r = 0; r < 4; r++) {
                size_t idx = (size_t)(b * 256 + n0 + r) * 768 + og;
                float v = 0.5f * res[i][j][r] + resid[idx];
                xout[idx] = v;
                if (xbout) xbout[idx] = f2bf(v);
            }
        }
}

// ---------------- P10: e2 streaming MFMA --------------------------------------
// e2[edge][o] = g[edge][0:32] @ Mcat[32][384], g[k]=c[k>>3]*e7[k&7] (e7[7]=0).
// A-frag: lane l -> row=l&15 (edge), k=(l>>4)*8+j  =>  hh=l>>4 uniform/lane!
// grid (512 edgeblocks of 256, 3 colgroups of 128 outs), 256 thr = 4 waves.
__global__ __launch_bounds__(256) void e2_kernel(const float* __restrict__ e,
                                                 const unsigned short* __restrict__ att1b,
                                                 const unsigned short* __restrict__ att2b,
                                                 const unsigned short* __restrict__ Bfrag,
                                                 float* __restrict__ e2out) {
    __shared__ unsigned short bl[8 * 64 * 8];
    const int t = threadIdx.x, cg = blockIdx.y;
    for (int idx = t; idx < 512; idx += 256)
        *(bf16x8*)&bl[idx * 8] = *(const bf16x8*)&Bfrag[(size_t)(cg * 512 + idx) * 8];
    __syncthreads();
    const int wv = t >> 6, l = t & 63, lr = l & 15, lq = l >> 4;
    const int h1 = lq >> 1, h2 = lq & 1;
    bf16x8 bfr[8];
#pragma unroll
    for (int i = 0; i < 8; i++) bfr[i] = *(const bf16x8*)&bl[(i * 64 + l) * 8];
    const f32x4 zero = {0, 0, 0, 0};
    for (int g = 0; g < 4; g++) {
        const int ebase = blockIdx.x * 256 + g * 64 + wv * 16;
        const int eidx = ebase + lr;
        const int b = eidx >> 16, nm = eidx & 65535;
        float a1 = bf2f(att1b[(size_t)(b * 2 + h1) * 65536 + nm]);
        float a2 = bf2f(att2b[(size_t)(b * 2 + h2) * 65536 + nm]);
        float c = a1 * a2;
        const float* ep = e + (size_t)eidx * 7;
        unsigned short av[8];
#pragma unroll
        for (int j = 0; j < 7; j++) av[j] = f2bf(c * ep[j]);
        av[7] = 0;
        bf16x8 afr = *(bf16x8*)av;
#pragma unroll
        for (int i = 0; i < 8; i++) {
            f32x4 accv = __builtin_amdgcn_mfma_f32_16x16x32_bf16(afr, bfr[i], zero, 0, 0, 0);
            int o = (cg * 8 + i) * 16 + lr;
#pragma unroll
            for (int r = 0; r < 4; r++) {
                size_t erow = (size_t)ebase + lq * 4 + r;
                e2out[erow * 384 + o] = accv[r];
            }
        }
    }
}

// ---------------------------------------------------------------------------
extern "C" void kernel_launch(void* const* d_in, const int* in_sizes, int n_in,
                              void* d_out, int out_size, void* d_ws, size_t ws_size,
                              hipStream_t stream) {
    const float* x   = (const float*)d_in[0];
    const int*   adj = (const int*)d_in[1];
    const float* e   = (const float*)d_in[2];
    const float* W1  = (const float*)d_in[3];
    const float* We1 = (const float*)d_in[4];
    const float* a1s = (const float*)d_in[5];
    const float* a1d = (const float*)d_in[6];
    const float* a1e = (const float*)d_in[7];
    const float* W2  = (const float*)d_in[8];
    const float* We2 = (const float*)d_in[9];
    const float* a2s = (const float*)d_in[10];
    const float* a2d = (const float*)d_in[11];
    const float* a2e = (const float*)d_in[12];

    float* out   = (float*)d_out;
    float* x2out = out;                  // [2][256][768]
    float* e2out = out + 393216;         // [2][256][256][384]

    // persistent scratch in d_ws
    char* ws = (char*)d_ws;
    float*          q     = (float*)(ws + 0);        // [4][2][768]  24576 B
    float*          u1    = (float*)(ws + 24576);    // [2][8]       64 B
    float*          wbuf  = (float*)(ws + 24640);    // [2][2][8]    128 B
    float*          Mcat  = (float*)(ws + 24832);    // [32][384]    49152 B
    unsigned short* Bfrag = (unsigned short*)(ws + 73984);   // [24][64][8] 24576 B
    float*          s1s   = (float*)(ws + 98560);
    float*          s1d   = (float*)(ws + 102656);
    float*          s2s   = (float*)(ws + 106752);
    float*          s2d   = (float*)(ws + 110848);
    unsigned short* att1b = (unsigned short*)(ws + 114944);  // [2][2][256][256]
    unsigned short* att2b = (unsigned short*)(ws + 639232);

    // large transients live in the e2 output region (overwritten last by e2_kernel)
    char* sc = (char*)e2out;
    unsigned short* W1T  = (unsigned short*)(sc + 0);        // [2][768][768]
    unsigned short* W2T  = (unsigned short*)(sc + 2359296);
    unsigned short* xb   = (unsigned short*)(sc + 4718592);  // [512][768]
    unsigned short* xb1  = (unsigned short*)(sc + 5505024);
    unsigned short* WhT1 = (unsigned short*)(sc + 6291456);  // [2][2][768][256]
    unsigned short* WhT2 = (unsigned short*)(sc + 7864320);
    float*          x1   = (float*)(sc + 9437184);           // [512][768]

    transpose_w<<<dim3(12, 12, 2), 256, 0, stream>>>(W1, W1T);
    transpose_w<<<dim3(12, 12, 2), 256, 0, stream>>>(W2, W2T);
    cvt_bf16<<<384, 256, 0, stream>>>(x, xb, 393216);
    precompute<<<577, 256, 0, stream>>>(W1, W2, We1, We2, a1s, a1d, a1e, a2s, a2d, a2e,
                                        q, u1, Mcat);
    finalize_pre<<<1, 64, 0, stream>>>(Mcat, a2e, wbuf, Bfrag);
    sdots<<<dim3(256, 2), 256, 0, stream>>>(x, q + 0, q + 1536, s1s, s1d);
    att_l1<<<dim3(256, 2, 2), 256, 0, stream>>>(e, adj, s1s, s1d, u1, att1b);
    gemm_xw<<<dim3(8, 12, 2), 256, 0, stream>>>(xb, W1T, WhT1);
    gemm_att<<<dim3(4, 12, 2), 256, 0, stream>>>(att1b, WhT1, x, x1, xb1);
    gemm_xw<<<dim3(8, 12, 2), 256, 0, stream>>>(xb1, W2T, WhT2);
    sdots<<<dim3(256, 2), 256, 0, stream>>>(x1, q + 3072, q + 4608, s2s, s2d);
    att_l2<<<dim3(256, 2, 2), 256, 0, stream>>>(e, adj, s2s, s2d, wbuf, att1b, att2b);
    gemm_att<<<dim3(4, 12, 2), 256, 0, stream>>>(att2b, WhT2, x, x2out, (unsigned short*)nullptr);
    e2_kernel<<<dim3(512, 3), 256, 0, stream>>>(e, att1b, att2b, Bfrag, e2out);
}

// Round 3
// 118.281 us; speedup vs baseline: 1.2115x; 1.2115x over previous
//
#include <hip/hip_runtime.h>
#include <hip/hip_bf16.h>
#include <cstddef>

// ---------------------------------------------------------------------------
// GAT 2-layer fused implementation for MI355X (gfx950).  Round 3:
//  - 8 horizontally-fused stages (was 14 serial launches)
//  - e2 MFMA operand swap -> dwordx4 stores (col=edge, rows=4 consecutive o)
//  - WhT2 moved to tail of e2out so gemm_att2 co-runs with e2 main
//  - shfl-based wave reductions in att/sdots (2 syncs instead of 16)
//  - finalize (w, Bfrag) parallelized over 25 blocks
// ---------------------------------------------------------------------------

typedef __attribute__((ext_vector_type(8))) short bf16x8;
typedef __attribute__((ext_vector_type(4))) short bf16x4;
typedef __attribute__((ext_vector_type(4))) float f32x4;
typedef unsigned short us;

#define DEVINL static __device__ __forceinline__

DEVINL us f2bf(float f) {
    union { float f; unsigned u; } v; v.f = f;
    return (us)((v.u + 0x7FFFu + ((v.u >> 16) & 1u)) >> 16); // RNE
}
DEVINL float bf2f(us b) {
    union { unsigned u; float f; } v; v.u = ((unsigned)b) << 16; return v.f;
}
DEVINL float wredmax(float v) {
#pragma unroll
    for (int s = 32; s; s >>= 1) v = fmaxf(v, __shfl_xor(v, s));
    return v;
}
DEVINL float wredsum(float v) {
#pragma unroll
    for (int s = 32; s; s >>= 1) v += __shfl_xor(v, s);
    return v;
}

// ---------------- transpose W [h][f][o] f32 -> WT [h][o][f] bf16 ------------
DEVINL void transpose_body(const float* __restrict__ W, us* __restrict__ WT, int bb) {
    __shared__ us tile[64][65];
    const int ft = (bb % 12) * 64, ot = ((bb / 12) % 12) * 64, h = bb / 144;
    const int t = threadIdx.x;
    const float* Wh = W + (size_t)h * 768 * 768;
    us* WTh = WT + (size_t)h * 768 * 768;
#pragma unroll
    for (int i = 0; i < 16; i++) {
        int idx = t + i * 256, r = idx >> 6, c = idx & 63;
        tile[c][r] = f2bf(Wh[(ft + r) * 768 + ot + c]);
    }
    __syncthreads();
#pragma unroll
    for (int i = 0; i < 16; i++) {
        int idx = t + i * 256, r = idx >> 6, c = idx & 63;
        WTh[(ot + r) * 768 + ft + c] = tile[r][c];
    }
}

// ---------------- f32 -> bf16 convert (x4) ----------------------------------
DEVINL void cvt_body(const float* __restrict__ in, us* __restrict__ out, int blk) {
    int i = (blk * 256 + threadIdx.x) * 4;
    float4 v = *(const float4*)&in[i];
    us pk[4] = {f2bf(v.x), f2bf(v.y), f2bf(v.z), f2bf(v.w)};
    *(bf16x4*)&out[i] = *(bf16x4*)pk;
}

// ---------------- precompute q vectors, u1, Mcat ----------------------------
DEVINL void pre_body(const float* __restrict__ W1, const float* __restrict__ W2,
                     const float* __restrict__ We1, const float* __restrict__ We2,
                     const float* __restrict__ a1s, const float* __restrict__ a1d,
                     const float* __restrict__ a1e, const float* __restrict__ a2s,
                     const float* __restrict__ a2d,
                     float* __restrict__ q, float* __restrict__ u1,
                     float* __restrict__ Mcat, int blk) {
    const int g = blk * 32 + (threadIdx.x >> 3);
    const int lane = threadIdx.x & 7;
    float acc = 0.0f;
    if (g < 6144) {
        int vec = g / 1536, rem = g % 1536, h = rem / 768, f = rem % 768;
        const float* W = (vec < 2) ? W1 : W2;
        const float* a = (vec == 0) ? a1s : (vec == 1) ? a1d : (vec == 2) ? a2s : a2d;
        const float* wr = W + (size_t)(h * 768 + f) * 768;
        const float* ar = a + h * 768;
        for (int o = lane; o < 768; o += 8) acc += wr[o] * ar[o];
        for (int s = 4; s; s >>= 1) acc += __shfl_down(acc, s, 8);
        if (lane == 0) q[g] = acc;
    } else if (g < 6160) {
        int g2 = g - 6144, h = g2 >> 3, k = g2 & 7;
        if (k < 7) {
            const float* wr = We1 + (h * 7 + k) * 384;
            const float* ar = a1e + h * 384;
            for (int o = lane; o < 384; o += 8) acc += wr[o] * ar[o];
        }
        for (int s = 4; s; s >>= 1) acc += __shfl_down(acc, s, 8);
        if (lane == 0) u1[g2] = acc;
    } else if (g < 18448) {
        int g3 = g - 6160, rk = g3 / 384, tc = g3 % 384;
        int hh = rk >> 3, kk = rk & 7, h1 = hh >> 1, h2 = hh & 1;
        if (kk < 7) {
            const float* wr = We1 + (h1 * 7 + kk) * 384;
            const float* w2c = We2 + (size_t)h2 * 384 * 384 + tc;
            for (int o = lane; o < 384; o += 8) acc += wr[o] * w2c[o * 384];
            acc *= 0.25f; // 1/H^2
        }
        for (int s = 4; s; s >>= 1) acc += __shfl_down(acc, s, 8);
        if (lane == 0) Mcat[g3] = acc;
    }
}

// ---------------- w[h1][h2][8] (block 0 of stage2) --------------------------
DEVINL void wcalc_body(const float* __restrict__ Mcat, const float* __restrict__ a2e,
                       float* __restrict__ w) {
    const int t = threadIdx.x, g = t >> 3, lane = t & 7; // 32 groups x 8 lanes
    int hh = g >> 3, k = g & 7, h2 = hh & 1;
    float acc = 0.0f;
    if (k < 7)
        for (int o = lane; o < 384; o += 8) acc += Mcat[(hh * 8 + k) * 384 + o] * a2e[h2 * 384 + o];
    for (int s = 4; s; s >>= 1) acc += __shfl_down(acc, s, 8);
    if (lane == 0) w[g] = 2.0f * acc; // * H
}

// ---------------- Bfrag[ct][64][8] from Mcat --------------------------------
DEVINL void bfrag_body(const float* __restrict__ Mcat, us* __restrict__ Bfrag, int ct) {
    const int l = threadIdx.x;
    if (l < 64) {
        us pk[8];
#pragma unroll
        for (int j = 0; j < 8; j++)
            pk[j] = f2bf(Mcat[((l >> 4) * 8 + j) * 384 + ct * 16 + (l & 15)]);
        *(bf16x8*)&Bfrag[(ct * 64 + l) * 8] = *(bf16x8*)pk;
    }
}

// ---------------- s_src/s_dst dots (f32), shfl-reduced ----------------------
DEVINL void sdots_body(const float* __restrict__ x, const float* __restrict__ qs,
                       const float* __restrict__ qd, float* __restrict__ out_s,
                       float* __restrict__ out_d, int n, int b) {
    const int t = threadIdx.x, wv = t >> 6;
    const float* xr = x + (size_t)(b * 256 + n) * 768;
    float a0 = 0, a1 = 0, a2 = 0, a3 = 0;
#pragma unroll
    for (int i = 0; i < 3; i++) {
        int k = i * 256 + t;
        float xv = xr[k];
        a0 += xv * qs[k];
        a1 += xv * qs[768 + k];
        a2 += xv * qd[k];
        a3 += xv * qd[768 + k];
    }
    a0 = wredsum(a0); a1 = wredsum(a1); a2 = wredsum(a2); a3 = wredsum(a3);
    __shared__ float part[4][4];
    if ((t & 63) == 0) { part[wv][0] = a0; part[wv][1] = a1; part[wv][2] = a2; part[wv][3] = a3; }
    __syncthreads();
    if (t == 0) {
        float r0 = 0, r1 = 0, r2 = 0, r3 = 0;
#pragma unroll
        for (int i = 0; i < 4; i++) { r0 += part[i][0]; r1 += part[i][1]; r2 += part[i][2]; r3 += part[i][3]; }
        out_s[(b * 2 + 0) * 256 + n] = r0;
        out_s[(b * 2 + 1) * 256 + n] = r1;
        out_d[(b * 2 + 0) * 256 + n] = r2;
        out_d[(b * 2 + 1) * 256 + n] = r3;
    }
}

// ---------------- attention softmax (shared by L1/L2) -----------------------
DEVINL void att_finish(float sc, us* __restrict__ attb, size_t outbase) {
    const int m = threadIdx.x, wv = m >> 6;
    __shared__ float sm[4], ssu[4];
    float wm_ = wredmax(sc);
    if ((m & 63) == 0) sm[wv] = wm_;
    __syncthreads();
    float mx = fmaxf(fmaxf(sm[0], sm[1]), fmaxf(sm[2], sm[3]));
    float ex = __expf(sc - mx);
    float ws = wredsum(ex);
    if ((m & 63) == 0) ssu[wv] = ws;
    __syncthreads();
    float inv = 1.0f / (ssu[0] + ssu[1] + ssu[2] + ssu[3]);
    attb[outbase + m] = f2bf(ex * inv);
}

DEVINL void att1_body(const float* __restrict__ e, const int* __restrict__ adj,
                      const float* __restrict__ s_s, const float* __restrict__ s_d,
                      const float* __restrict__ u1, us* __restrict__ attb,
                      int n, int h, int b) {
    const int m = threadIdx.x;
    float ss = s_s[(b * 2 + h) * 256 + n];
    float sd = s_d[(b * 2 + h) * 256 + m];
    const float* ep = e + ((size_t)(b * 256 + n) * 256 + m) * 7;
    float se = 0.0f;
#pragma unroll
    for (int k = 0; k < 7; k++) se += ep[k] * u1[h * 8 + k];
    float sc = ss + sd + se;
    sc = sc > 0.0f ? sc : 0.2f * sc;
    sc = adj[(size_t)(b * 256 + n) * 256 + m] > 0 ? sc : -9e15f;
    att_finish(sc, attb, ((size_t)(b * 2 + h) * 256 + n) * 256);
}

DEVINL void att2_body(const float* __restrict__ e, const int* __restrict__ adj,
                      const float* __restrict__ s_s, const float* __restrict__ s_d,
                      const float* __restrict__ w, const us* __restrict__ att1b,
                      us* __restrict__ attb, int n, int h, int b) {
    const int m = threadIdx.x;
    float ss = s_s[(b * 2 + h) * 256 + n];
    float sd = s_d[(b * 2 + h) * 256 + m];
    const float* ep = e + ((size_t)(b * 256 + n) * 256 + m) * 7;
    float se = 0.0f;
#pragma unroll
    for (int h1 = 0; h1 < 2; h1++) {
        float ew = 0.0f;
#pragma unroll
        for (int k = 0; k < 7; k++) ew += ep[k] * w[(h1 * 2 + h) * 8 + k];
        float a1 = bf2f(att1b[((size_t)(b * 2 + h1) * 256 + n) * 256 + m]);
        se += a1 * ew;
    }
    float sc = ss + sd + se;
    sc = sc > 0.0f ? sc : 0.2f * sc;
    sc = adj[(size_t)(b * 256 + n) * 256 + m] > 0 ? sc : -9e15f;
    att_finish(sc, attb, ((size_t)(b * 2 + h) * 256 + n) * 256);
}

// ---------------- Wh^T = (x @ W)^T via bf16 MFMA ----------------------------
DEVINL void gemm_xw_body(const us* __restrict__ A, const us* __restrict__ BT,
                         us* __restrict__ WhT, int mt, int ot, int h) {
    const int t = threadIdx.x, wv = t >> 6, l = t & 63;
    const int wm = wv >> 1, wn = wv & 1, lr = l & 15, lk = l >> 4;
    __shared__ us As[64][40];
    __shared__ us Bs[64][40];
    const int arow = t >> 2, acol = (t & 3) * 8;
    const us* Bh = BT + (size_t)h * 768 * 768;
    f32x4 acc[2][2];
#pragma unroll
    for (int i = 0; i < 2; i++)
#pragma unroll
        for (int j = 0; j < 2; j++) acc[i][j] = (f32x4){0, 0, 0, 0};
    for (int k0 = 0; k0 < 768; k0 += 32) {
        __syncthreads();
        *(bf16x8*)&As[arow][acol] = *(const bf16x8*)&A[(size_t)(mt * 64 + arow) * 768 + k0 + acol];
        *(bf16x8*)&Bs[arow][acol] = *(const bf16x8*)&Bh[(size_t)(ot * 64 + arow) * 768 + k0 + acol];
        __syncthreads();
        bf16x8 af[2], bfv[2];
#pragma unroll
        for (int i = 0; i < 2; i++) af[i] = *(const bf16x8*)&As[wm * 32 + i * 16 + lr][lk * 8];
#pragma unroll
        for (int j = 0; j < 2; j++) bfv[j] = *(const bf16x8*)&Bs[wn * 32 + j * 16 + lr][lk * 8];
#pragma unroll
        for (int i = 0; i < 2; i++)
#pragma unroll
            for (int j = 0; j < 2; j++)
                acc[i][j] = __builtin_amdgcn_mfma_f32_16x16x32_bf16(af[i], bfv[j], acc[i][j], 0, 0, 0);
    }
#pragma unroll
    for (int i = 0; i < 2; i++)
#pragma unroll
        for (int j = 0; j < 2; j++) {
            int n0 = mt * 64 + wm * 32 + i * 16 + lk * 4;
            int og = ot * 64 + wn * 32 + j * 16 + lr;
            int b = n0 >> 8, n = n0 & 255;
            us pk[4];
#pragma unroll
            for (int r = 0; r < 4; r++) pk[r] = f2bf(acc[i][j][r]);
            *(bf16x4*)&WhT[((size_t)(b * 2 + h) * 768 + og) * 256 + n] = *(bf16x4*)pk;
        }
}

// ---------------- x' = 0.5*(elu(att@Wh)_h0 + elu_h1) + resid ----------------
DEVINL void gemm_att_body(const us* __restrict__ attb, const us* __restrict__ WhT,
                          const float* __restrict__ resid, float* __restrict__ xout,
                          us* __restrict__ xbout, int mt, int ot, int b) {
    const int t = threadIdx.x, wv = t >> 6, l = t & 63;
    const int wm = wv >> 1, wn = wv & 1, lr = l & 15, lk = l >> 4;
    __shared__ us As2[64][40];
    __shared__ us Bs2[64][40];
    const int arow = t >> 2, acol = (t & 3) * 8;
    float res[2][2][4] = {};
    for (int h = 0; h < 2; h++) {
        const us* Ah = attb + (size_t)(b * 2 + h) * 256 * 256;
        const us* Bh = WhT + (size_t)(b * 2 + h) * 768 * 256;
        f32x4 acc[2][2];
#pragma unroll
        for (int i = 0; i < 2; i++)
#pragma unroll
            for (int j = 0; j < 2; j++) acc[i][j] = (f32x4){0, 0, 0, 0};
        for (int k0 = 0; k0 < 256; k0 += 32) {
            __syncthreads();
            *(bf16x8*)&As2[arow][acol] = *(const bf16x8*)&Ah[(size_t)(mt * 64 + arow) * 256 + k0 + acol];
            *(bf16x8*)&Bs2[arow][acol] = *(const bf16x8*)&Bh[(size_t)(ot * 64 + arow) * 256 + k0 + acol];
            __syncthreads();
            bf16x8 af[2], bfv[2];
#pragma unroll
            for (int i = 0; i < 2; i++) af[i] = *(const bf16x8*)&As2[wm * 32 + i * 16 + lr][lk * 8];
#pragma unroll
            for (int j = 0; j < 2; j++) bfv[j] = *(const bf16x8*)&Bs2[wn * 32 + j * 16 + lr][lk * 8];
#pragma unroll
            for (int i = 0; i < 2; i++)
#pragma unroll
                for (int j = 0; j < 2; j++)
                    acc[i][j] = __builtin_amdgcn_mfma_f32_16x16x32_bf16(af[i], bfv[j], acc[i][j], 0, 0, 0);
        }
#pragma unroll
        for (int i = 0; i < 2; i++)
#pragma unroll
            for (int j = 0; j < 2; j++)
#pragma unroll
                for (int r = 0; r < 4; r++) {
                    float v = acc[i][j][r];
                    res[i][j][r] += (v > 0.0f ? v : (expf(v) - 1.0f)); // elu
                }
        __syncthreads();
    }
#pragma unroll
    for (int i = 0; i < 2; i++)
#pragma unroll
        for (int j = 0; j < 2; j++) {
            int n0 = mt * 64 + wm * 32 + i * 16 + lk * 4;
            int og = ot * 64 + wn * 32 + j * 16 + lr;
#pragma unroll
            for (int r = 0; r < 4; r++) {
                size_t idx = (size_t)(b * 256 + n0 + r) * 768 + og;
                float v = 0.5f * res[i][j][r] + resid[idx];
                xout[idx] = v;
                if (xbout) xbout[idx] = f2bf(v);
            }
        }
}

// ---------------- e2 streaming MFMA (swapped operands: col=edge) ------------
// D = Mcat^T_tile[16 o x 32 k] * g^T[32 k x 16 edges]; lane stores float4 of
// 4 consecutive o for its edge. Per store instr: 16 rows x 64B contiguous.
DEVINL void e2_body(const float* __restrict__ e, const us* __restrict__ att1b,
                    const us* __restrict__ att2b, const us* __restrict__ Bfrag,
                    float* __restrict__ e2out, int eb, int cg) {
    __shared__ us bl[8 * 64 * 8];
    const int t = threadIdx.x;
    for (int idx = t; idx < 512; idx += 256)
        *(bf16x8*)&bl[idx * 8] = *(const bf16x8*)&Bfrag[(size_t)(cg * 512 + idx) * 8];
    __syncthreads();
    const int wv = t >> 6, l = t & 63, le = l & 15, lq = l >> 4;
    const int h1 = lq >> 1, h2 = lq & 1;
    bf16x8 bfr[8];
#pragma unroll
    for (int i = 0; i < 8; i++) bfr[i] = *(const bf16x8*)&bl[(i * 64 + l) * 8];
    const f32x4 zero = {0, 0, 0, 0};
    for (int g = 0; g < 4; g++) {
        const int ebase = eb * 256 + g * 64 + wv * 16;
        const int eidx = ebase + le;
        const int b = eidx >> 16, nm = eidx & 65535;
        float a1 = bf2f(att1b[(size_t)(b * 2 + h1) * 65536 + nm]);
        float a2 = bf2f(att2b[(size_t)(b * 2 + h2) * 65536 + nm]);
        float c = a1 * a2;
        const float* ep = e + (size_t)eidx * 7;
        us av[8];
#pragma unroll
        for (int j = 0; j < 7; j++) av[j] = f2bf(c * ep[j]);
        av[7] = 0;
        bf16x8 gfr = *(bf16x8*)av;
#pragma unroll
        for (int i = 0; i < 8; i++) {
            f32x4 accv = __builtin_amdgcn_mfma_f32_16x16x32_bf16(bfr[i], gfr, zero, 0, 0, 0);
            int o0 = cg * 128 + i * 16 + lq * 4;
            *(f32x4*)&e2out[(size_t)eidx * 384 + o0] = accv;
        }
    }
}

// ========================= stage kernels ====================================
__global__ __launch_bounds__(256) void stage1(
    const float* W1, const float* W2, const float* We1, const float* We2,
    const float* a1s, const float* a1d, const float* a1e,
    const float* a2s, const float* a2d,
    const float* x, us* W1T, us* W2T, us* xb,
    float* q, float* u1, float* Mcat) {
    int b = blockIdx.x;
    if (b < 288)       transpose_body(W1, W1T, b);
    else if (b < 576)  transpose_body(W2, W2T, b - 288);
    else if (b < 960)  cvt_body(x, xb, b - 576);
    else               pre_body(W1, W2, We1, We2, a1s, a1d, a1e, a2s, a2d, q, u1, Mcat, b - 960);
}

__global__ __launch_bounds__(256) void stage2(
    const float* Mcat, const float* a2e, float* wbuf, us* Bfrag,
    const float* x, const float* qs, const float* qd, float* s1s, float* s1d) {
    int b = blockIdx.x;
    if (b < 1)        wcalc_body(Mcat, a2e, wbuf);
    else if (b < 25)  bfrag_body(Mcat, Bfrag, b - 1);
    else { int i = b - 25; sdots_body(x, qs, qd, s1s, s1d, i & 255, i >> 8); }
}

__global__ __launch_bounds__(256) void stage3(
    const float* e, const int* adj, const float* s1s, const float* s1d,
    const float* u1, us* att1b, const us* xb, const us* W1T, us* WhT1) {
    int b = blockIdx.x;
    if (b < 1024) att1_body(e, adj, s1s, s1d, u1, att1b, b & 255, (b >> 8) & 1, b >> 9);
    else { int g = b - 1024; gemm_xw_body(xb, W1T, WhT1, g & 7, (g >> 3) % 12, g / 96); }
}

__global__ __launch_bounds__(256) void stage4(
    const us* att1b, const us* WhT1, const float* x, float* x1, us* xb1) {
    int b = blockIdx.x;
    gemm_att_body(att1b, WhT1, x, x1, xb1, b & 3, (b >> 2) % 12, b / 48);
}

__global__ __launch_bounds__(256) void stage5(
    const float* x1, const float* qs, const float* qd, float* s2s, float* s2d,
    const us* xb1, const us* W2T, us* WhT2) {
    int b = blockIdx.x;
    if (b < 512) sdots_body(x1, qs, qd, s2s, s2d, b & 255, b >> 8);
    else { int g = b - 512; gemm_xw_body(xb1, W2T, WhT2, g & 7, (g >> 3) % 12, g / 96); }
}

__global__ __launch_bounds__(256) void stage6(
    const float* e, const int* adj, const float* s2s, const float* s2d,
    const float* wbuf, const us* att1b, us* att2b) {
    int b = blockIdx.x;
    att2_body(e, adj, s2s, s2d, wbuf, att1b, att2b, b & 255, (b >> 8) & 1, b >> 9);
}

__global__ __launch_bounds__(256) void stage7(
    const us* att2b, const us* WhT2, const float* x, float* x2out,
    const float* e, const us* att1b, const us* Bfrag, float* e2out) {
    int b = blockIdx.x;
    if (b < 96) gemm_att_body(att2b, WhT2, x, x2out, (us*)nullptr, b & 3, (b >> 2) % 12, b / 48);
    else { int idx = b - 96; e2_body(e, att1b, att2b, Bfrag, e2out, idx / 3, idx % 3); }
}

__global__ __launch_bounds__(256) void stage8(
    const float* e, const us* att1b, const us* att2b, const us* Bfrag, float* e2out) {
    int b = blockIdx.x;
    e2_body(e, att1b, att2b, Bfrag, e2out, 508 + b / 3, b % 3);
}

// ---------------------------------------------------------------------------
extern "C" void kernel_launch(void* const* d_in, const int* in_sizes, int n_in,
                              void* d_out, int out_size, void* d_ws, size_t ws_size,
                              hipStream_t stream) {
    const float* x   = (const float*)d_in[0];
    const int*   adj = (const int*)d_in[1];
    const float* e   = (const float*)d_in[2];
    const float* W1  = (const float*)d_in[3];
    const float* We1 = (const float*)d_in[4];
    const float* a1s = (const float*)d_in[5];
    const float* a1d = (const float*)d_in[6];
    const float* a1e = (const float*)d_in[7];
    const float* W2  = (const float*)d_in[8];
    const float* We2 = (const float*)d_in[9];
    const float* a2s = (const float*)d_in[10];
    const float* a2d = (const float*)d_in[11];
    const float* a2e = (const float*)d_in[12];

    float* out   = (float*)d_out;
    float* x2out = out;                  // [2][256][768]
    float* e2out = out + 393216;         // [2][256][256][384] edges x 384

    // persistent scratch in d_ws
    char* ws = (char*)d_ws;
    float* q     = (float*)(ws + 0);        // [4][2][768]
    float* u1    = (float*)(ws + 24576);    // [2][8]
    float* wbuf  = (float*)(ws + 24640);    // [2][2][8]
    float* Mcat  = (float*)(ws + 24832);    // [32][384]
    us*    Bfrag = (us*)(ws + 73984);       // [24][64][8]
    float* s1s   = (float*)(ws + 98560);
    float* s1d   = (float*)(ws + 102656);
    float* s2s   = (float*)(ws + 106752);
    float* s2d   = (float*)(ws + 110848);
    us*    att1b = (us*)(ws + 114944);      // [2][2][256][256]
    us*    att2b = (us*)(ws + 639232);

    // large transients live in the e2 output region.
    // WhT2 sits in the TAIL (last 4 edge-blocks) so stage7's gemm_att2 can
    // read it while e2 main (eb<508) streams; stage8 fills the tail last.
    char* sc = (char*)e2out;
    us*    W1T  = (us*)(sc + 0);            // [2][768][768] bf16
    us*    W2T  = (us*)(sc + 2359296);
    us*    xb   = (us*)(sc + 4718592);      // [512][768] bf16
    us*    xb1  = (us*)(sc + 5505024);
    us*    WhT1 = (us*)(sc + 6291456);      // [2][2][768][256] bf16
    float* x1   = (float*)(sc + 7864320);   // [512][768] f32
    us*    WhT2 = (us*)(e2out + 49938432);  // tail 1.5MB = edges [130048,131072)

    stage1<<<1537, 256, 0, stream>>>(W1, W2, We1, We2, a1s, a1d, a1e, a2s, a2d,
                                     x, W1T, W2T, xb, q, u1, Mcat);
    stage2<<<537, 256, 0, stream>>>(Mcat, a2e, wbuf, Bfrag, x, q + 0, q + 1536, s1s, s1d);
    stage3<<<1216, 256, 0, stream>>>(e, adj, s1s, s1d, u1, att1b, xb, W1T, WhT1);
    stage4<<<96, 256, 0, stream>>>(att1b, WhT1, x, x1, xb1);
    stage5<<<704, 256, 0, stream>>>(x1, q + 3072, q + 4608, s2s, s2d, xb1, W2T, WhT2);
    stage6<<<1024, 256, 0, stream>>>(e, adj, s2s, s2d, wbuf, att1b, att2b);
    stage7<<<1620, 256, 0, stream>>>(att2b, WhT2, x, x2out, e, att1b, Bfrag, e2out);
    stage8<<<12, 256, 0, stream>>>(e, att1b, att2b, Bfrag, e2out);
}

// Round 4
// 106.016 us; speedup vs baseline: 1.3516x; 1.1157x over previous
//
#include <hip/hip_runtime.h>
#include <hip/hip_bf16.h>
#include <cstddef>

// ---------------------------------------------------------------------------
// GAT 2-layer fused, MI355X (gfx950).  Round 4:
//  - all transients in d_ws (~12MB of ~600MB) -> no out-region aliasing
//  - att1/att2: both heads per block, e-row staged in LDS (512 blocks)
//  - e2row: one block per (b,n) row, full 384 cols, Bfrag in LDS once
//  - gemm_att: 32x64 tiles -> 192 blocks
//  - 7 kernels total
// ---------------------------------------------------------------------------

typedef __attribute__((ext_vector_type(8))) short bf16x8;
typedef __attribute__((ext_vector_type(4))) short bf16x4;
typedef __attribute__((ext_vector_type(4))) float f32x4;
typedef unsigned short us;

#define DEVINL static __device__ __forceinline__

DEVINL us f2bf(float f) {
    union { float f; unsigned u; } v; v.f = f;
    return (us)((v.u + 0x7FFFu + ((v.u >> 16) & 1u)) >> 16); // RNE
}
DEVINL float bf2f(us b) {
    union { unsigned u; float f; } v; v.u = ((unsigned)b) << 16; return v.f;
}
DEVINL float wredmax(float v) {
#pragma unroll
    for (int s = 32; s; s >>= 1) v = fmaxf(v, __shfl_xor(v, s));
    return v;
}
DEVINL float wredsum(float v) {
#pragma unroll
    for (int s = 32; s; s >>= 1) v += __shfl_xor(v, s);
    return v;
}

// ---------------- transpose W [h][f][o] f32 -> WT [h][o][f] bf16 ------------
DEVINL void transpose_body(const float* __restrict__ W, us* __restrict__ WT, int bb) {
    __shared__ us tile[64][65];
    const int ft = (bb % 12) * 64, ot = ((bb / 12) % 12) * 64, h = bb / 144;
    const int t = threadIdx.x;
    const float* Wh = W + (size_t)h * 768 * 768;
    us* WTh = WT + (size_t)h * 768 * 768;
#pragma unroll
    for (int i = 0; i < 16; i++) {
        int idx = t + i * 256, r = idx >> 6, c = idx & 63;
        tile[c][r] = f2bf(Wh[(ft + r) * 768 + ot + c]);
    }
    __syncthreads();
#pragma unroll
    for (int i = 0; i < 2; i++) {
        int idx = t + i * 256, r = idx >> 3, c0 = (idx & 7) * 8;
        us pk[8];
#pragma unroll
        for (int j = 0; j < 8; j++) pk[j] = tile[r][c0 + j];
        *(bf16x8*)&WTh[(ot + r) * 768 + ft + c0] = *(bf16x8*)pk;
    }
}

// ---------------- f32 -> bf16 convert (x8) ----------------------------------
DEVINL void cvt_body(const float* __restrict__ in, us* __restrict__ out, int blk) {
    int i = (blk * 256 + threadIdx.x) * 8;
    float4 v0 = *(const float4*)&in[i];
    float4 v1 = *(const float4*)&in[i + 4];
    us pk[8] = {f2bf(v0.x), f2bf(v0.y), f2bf(v0.z), f2bf(v0.w),
                f2bf(v1.x), f2bf(v1.y), f2bf(v1.z), f2bf(v1.w)};
    *(bf16x8*)&out[i] = *(bf16x8*)pk;
}

// ---------------- precompute q vectors, u1, Mcat ----------------------------
DEVINL void pre_body(const float* __restrict__ W1, const float* __restrict__ W2,
                     const float* __restrict__ We1, const float* __restrict__ We2,
                     const float* __restrict__ a1s, const float* __restrict__ a1d,
                     const float* __restrict__ a1e, const float* __restrict__ a2s,
                     const float* __restrict__ a2d,
                     float* __restrict__ q, float* __restrict__ u1,
                     float* __restrict__ Mcat, int blk) {
    const int g = blk * 32 + (threadIdx.x >> 3);
    const int lane = threadIdx.x & 7;
    float acc = 0.0f;
    if (g < 6144) {
        int vec = g / 1536, rem = g % 1536, h = rem / 768, f = rem % 768;
        const float* W = (vec < 2) ? W1 : W2;
        const float* a = (vec == 0) ? a1s : (vec == 1) ? a1d : (vec == 2) ? a2s : a2d;
        const float* wr = W + (size_t)(h * 768 + f) * 768;
        const float* ar = a + h * 768;
        for (int o = lane; o < 768; o += 8) acc += wr[o] * ar[o];
        for (int s = 4; s; s >>= 1) acc += __shfl_down(acc, s, 8);
        if (lane == 0) q[g] = acc;
    } else if (g < 6160) {
        int g2 = g - 6144, h = g2 >> 3, k = g2 & 7;
        if (k < 7) {
            const float* wr = We1 + (h * 7 + k) * 384;
            const float* ar = a1e + h * 384;
            for (int o = lane; o < 384; o += 8) acc += wr[o] * ar[o];
        }
        for (int s = 4; s; s >>= 1) acc += __shfl_down(acc, s, 8);
        if (lane == 0) u1[g2] = acc;
    } else if (g < 18448) {
        int g3 = g - 6160, rk = g3 / 384, tc = g3 % 384;
        int hh = rk >> 3, kk = rk & 7, h1 = hh >> 1, h2 = hh & 1;
        if (kk < 7) {
            const float* wr = We1 + (h1 * 7 + kk) * 384;
            const float* w2c = We2 + (size_t)h2 * 384 * 384 + tc;
            for (int o = lane; o < 384; o += 8) acc += wr[o] * w2c[o * 384];
            acc *= 0.25f; // 1/H^2
        }
        for (int s = 4; s; s >>= 1) acc += __shfl_down(acc, s, 8);
        if (lane == 0) Mcat[g3] = acc;
    }
}

// ---------------- w[h1][h2][8] ----------------------------------------------
DEVINL void wcalc_body(const float* __restrict__ Mcat, const float* __restrict__ a2e,
                       float* __restrict__ w) {
    const int t = threadIdx.x, g = t >> 3, lane = t & 7;
    int hh = g >> 3, k = g & 7, h2 = hh & 1;
    float acc = 0.0f;
    if (k < 7)
        for (int o = lane; o < 384; o += 8) acc += Mcat[(hh * 8 + k) * 384 + o] * a2e[h2 * 384 + o];
    for (int s = 4; s; s >>= 1) acc += __shfl_down(acc, s, 8);
    if (lane == 0) w[g] = 2.0f * acc; // * H
}

// ---------------- Bfrag[ct][64][8] from Mcat --------------------------------
DEVINL void bfrag_body(const float* __restrict__ Mcat, us* __restrict__ Bfrag, int ct) {
    const int l = threadIdx.x;
    if (l < 64) {
        us pk[8];
#pragma unroll
        for (int j = 0; j < 8; j++)
            pk[j] = f2bf(Mcat[((l >> 4) * 8 + j) * 384 + ct * 16 + (l & 15)]);
        *(bf16x8*)&Bfrag[(ct * 64 + l) * 8] = *(bf16x8*)pk;
    }
}

// ---------------- s_src/s_dst dots (f32), shfl-reduced ----------------------
DEVINL void sdots_body(const float* __restrict__ x, const float* __restrict__ qs,
                       const float* __restrict__ qd, float* __restrict__ out_s,
                       float* __restrict__ out_d, int n, int b) {
    const int t = threadIdx.x, wv = t >> 6;
    const float* xr = x + (size_t)(b * 256 + n) * 768;
    float a0 = 0, a1 = 0, a2 = 0, a3 = 0;
#pragma unroll
    for (int i = 0; i < 3; i++) {
        int k = i * 256 + t;
        float xv = xr[k];
        a0 += xv * qs[k];
        a1 += xv * qs[768 + k];
        a2 += xv * qd[k];
        a3 += xv * qd[768 + k];
    }
    a0 = wredsum(a0); a1 = wredsum(a1); a2 = wredsum(a2); a3 = wredsum(a3);
    __shared__ float part[4][4];
    if ((t & 63) == 0) { part[wv][0] = a0; part[wv][1] = a1; part[wv][2] = a2; part[wv][3] = a3; }
    __syncthreads();
    if (t == 0) {
        float r0 = 0, r1 = 0, r2 = 0, r3 = 0;
#pragma unroll
        for (int i = 0; i < 4; i++) { r0 += part[i][0]; r1 += part[i][1]; r2 += part[i][2]; r3 += part[i][3]; }
        out_s[(b * 2 + 0) * 256 + n] = r0;
        out_s[(b * 2 + 1) * 256 + n] = r1;
        out_d[(b * 2 + 0) * 256 + n] = r2;
        out_d[(b * 2 + 1) * 256 + n] = r3;
    }
}

// ---------------- attention softmax, both heads per block -------------------
DEVINL void att_finish2(float sc0, float sc1, us* __restrict__ attb,
                        size_t base0, size_t base1) {
    const int t = threadIdx.x, wv = t >> 6;
    __shared__ float smax[2][4], ssum[2][4];
    float w0 = wredmax(sc0), w1 = wredmax(sc1);
    if ((t & 63) == 0) { smax[0][wv] = w0; smax[1][wv] = w1; }
    __syncthreads();
    float mx0 = fmaxf(fmaxf(smax[0][0], smax[0][1]), fmaxf(smax[0][2], smax[0][3]));
    float mx1 = fmaxf(fmaxf(smax[1][0], smax[1][1]), fmaxf(smax[1][2], smax[1][3]));
    float ex0 = __expf(sc0 - mx0), ex1 = __expf(sc1 - mx1);
    float su0 = wredsum(ex0), su1 = wredsum(ex1);
    if ((t & 63) == 0) { ssum[0][wv] = su0; ssum[1][wv] = su1; }
    __syncthreads();
    float i0 = 1.0f / (ssum[0][0] + ssum[0][1] + ssum[0][2] + ssum[0][3]);
    float i1 = 1.0f / (ssum[1][0] + ssum[1][1] + ssum[1][2] + ssum[1][3]);
    attb[base0 + t] = f2bf(ex0 * i0);
    attb[base1 + t] = f2bf(ex1 * i1);
}

DEVINL void att1_body(const float* __restrict__ e, const int* __restrict__ adj,
                      const float* __restrict__ s_s, const float* __restrict__ s_d,
                      const float* __restrict__ u1, us* __restrict__ attb,
                      int n, int bb) {
    __shared__ float eL[1792];
    const int t = threadIdx.x;
    const float* erow = e + (size_t)(bb * 256 + n) * 256 * 7;
#pragma unroll
    for (int i = 0; i < 7; i++) eL[t + i * 256] = erow[t + i * 256];
    __syncthreads();
    float ss0 = s_s[(bb * 2 + 0) * 256 + n], ss1 = s_s[(bb * 2 + 1) * 256 + n];
    float sd0 = s_d[(bb * 2 + 0) * 256 + t], sd1 = s_d[(bb * 2 + 1) * 256 + t];
    float se0 = 0, se1 = 0;
#pragma unroll
    for (int k = 0; k < 7; k++) {
        float ev = eL[t * 7 + k];
        se0 += ev * u1[k];
        se1 += ev * u1[8 + k];
    }
    float sc0 = ss0 + sd0 + se0, sc1 = ss1 + sd1 + se1;
    sc0 = sc0 > 0.0f ? sc0 : 0.2f * sc0;
    sc1 = sc1 > 0.0f ? sc1 : 0.2f * sc1;
    bool ok = adj[(size_t)(bb * 256 + n) * 256 + t] > 0;
    sc0 = ok ? sc0 : -9e15f;
    sc1 = ok ? sc1 : -9e15f;
    size_t base0 = ((size_t)(bb * 2 + 0) * 256 + n) * 256;
    size_t base1 = ((size_t)(bb * 2 + 1) * 256 + n) * 256;
    att_finish2(sc0, sc1, attb, base0, base1);
}

DEVINL void att2_body(const float* __restrict__ e, const int* __restrict__ adj,
                      const float* __restrict__ s_s, const float* __restrict__ s_d,
                      const float* __restrict__ w, const us* __restrict__ att1b,
                      us* __restrict__ attb, int n, int bb) {
    __shared__ float eL[1792];
    const int t = threadIdx.x;
    const float* erow = e + (size_t)(bb * 256 + n) * 256 * 7;
#pragma unroll
    for (int i = 0; i < 7; i++) eL[t + i * 256] = erow[t + i * 256];
    __syncthreads();
    float ss0 = s_s[(bb * 2 + 0) * 256 + n], ss1 = s_s[(bb * 2 + 1) * 256 + n];
    float sd0 = s_d[(bb * 2 + 0) * 256 + t], sd1 = s_d[(bb * 2 + 1) * 256 + t];
    float a10 = bf2f(att1b[((size_t)(bb * 2 + 0) * 256 + n) * 256 + t]);
    float a11 = bf2f(att1b[((size_t)(bb * 2 + 1) * 256 + n) * 256 + t]);
    float ew00 = 0, ew01 = 0, ew10 = 0, ew11 = 0; // ew[h1][h]
#pragma unroll
    for (int k = 0; k < 7; k++) {
        float ev = eL[t * 7 + k];
        ew00 += ev * w[0 * 8 + k];
        ew01 += ev * w[1 * 8 + k];
        ew10 += ev * w[2 * 8 + k];
        ew11 += ev * w[3 * 8 + k];
    }
    float sc0 = ss0 + sd0 + a10 * ew00 + a11 * ew10;
    float sc1 = ss1 + sd1 + a10 * ew01 + a11 * ew11;
    sc0 = sc0 > 0.0f ? sc0 : 0.2f * sc0;
    sc1 = sc1 > 0.0f ? sc1 : 0.2f * sc1;
    bool ok = adj[(size_t)(bb * 256 + n) * 256 + t] > 0;
    sc0 = ok ? sc0 : -9e15f;
    sc1 = ok ? sc1 : -9e15f;
    size_t base0 = ((size_t)(bb * 2 + 0) * 256 + n) * 256;
    size_t base1 = ((size_t)(bb * 2 + 1) * 256 + n) * 256;
    att_finish2(sc0, sc1, attb, base0, base1);
}

// ---------------- Wh^T = (x @ W)^T via bf16 MFMA (64x64 tiles) --------------
DEVINL void gemm_xw_body(const us* __restrict__ A, const us* __restrict__ BT,
                         us* __restrict__ WhT, int mt, int ot, int h) {
    const int t = threadIdx.x, wv = t >> 6, l = t & 63;
    const int wm = wv >> 1, wn = wv & 1, lr = l & 15, lk = l >> 4;
    __shared__ us As[64][40];
    __shared__ us Bs[64][40];
    const int arow = t >> 2, acol = (t & 3) * 8;
    const us* Bh = BT + (size_t)h * 768 * 768;
    f32x4 acc[2][2];
#pragma unroll
    for (int i = 0; i < 2; i++)
#pragma unroll
        for (int j = 0; j < 2; j++) acc[i][j] = (f32x4){0, 0, 0, 0};
    for (int k0 = 0; k0 < 768; k0 += 32) {
        __syncthreads();
        *(bf16x8*)&As[arow][acol] = *(const bf16x8*)&A[(size_t)(mt * 64 + arow) * 768 + k0 + acol];
        *(bf16x8*)&Bs[arow][acol] = *(const bf16x8*)&Bh[(size_t)(ot * 64 + arow) * 768 + k0 + acol];
        __syncthreads();
        bf16x8 af[2], bfv[2];
#pragma unroll
        for (int i = 0; i < 2; i++) af[i] = *(const bf16x8*)&As[wm * 32 + i * 16 + lr][lk * 8];
#pragma unroll
        for (int j = 0; j < 2; j++) bfv[j] = *(const bf16x8*)&Bs[wn * 32 + j * 16 + lr][lk * 8];
#pragma unroll
        for (int i = 0; i < 2; i++)
#pragma unroll
            for (int j = 0; j < 2; j++)
                acc[i][j] = __builtin_amdgcn_mfma_f32_16x16x32_bf16(af[i], bfv[j], acc[i][j], 0, 0, 0);
    }
#pragma unroll
    for (int i = 0; i < 2; i++)
#pragma unroll
        for (int j = 0; j < 2; j++) {
            int n0 = mt * 64 + wm * 32 + i * 16 + lk * 4;
            int og = ot * 64 + wn * 32 + j * 16 + lr;
            int b = n0 >> 8, n = n0 & 255;
            us pk[4];
#pragma unroll
            for (int r = 0; r < 4; r++) pk[r] = f2bf(acc[i][j][r]);
            *(bf16x4*)&WhT[((size_t)(b * 2 + h) * 768 + og) * 256 + n] = *(bf16x4*)pk;
        }
}

// ---------------- x' = 0.5*(elu(att@Wh)_h0+elu_h1)+resid (32x64 tiles) ------
DEVINL void gemm_att_body(const us* __restrict__ attb, const us* __restrict__ WhT,
                          const float* __restrict__ resid, float* __restrict__ xout,
                          us* __restrict__ xbout, int mt, int ot, int b) {
    const int t = threadIdx.x, wv = t >> 6, l = t & 63;
    const int wm = wv >> 1, wn = wv & 1, lr = l & 15, lk = l >> 4;
    __shared__ us As2[32][40];
    __shared__ us Bs2[64][40];
    float res[2][4] = {};
    for (int h = 0; h < 2; h++) {
        const us* Ah = attb + (size_t)(b * 2 + h) * 65536;
        const us* Bh = WhT + (size_t)(b * 2 + h) * 768 * 256;
        f32x4 acc[2];
        acc[0] = (f32x4){0, 0, 0, 0};
        acc[1] = (f32x4){0, 0, 0, 0};
        for (int k0 = 0; k0 < 256; k0 += 32) {
            __syncthreads();
            if (t < 128) {
                int ar = t >> 2, ac = (t & 3) * 8;
                *(bf16x8*)&As2[ar][ac] = *(const bf16x8*)&Ah[(size_t)(mt * 32 + ar) * 256 + k0 + ac];
            }
            {
                int br = t >> 2, bc = (t & 3) * 8;
                *(bf16x8*)&Bs2[br][bc] = *(const bf16x8*)&Bh[(size_t)(ot * 64 + br) * 256 + k0 + bc];
            }
            __syncthreads();
            bf16x8 af = *(const bf16x8*)&As2[wm * 16 + lr][lk * 8];
#pragma unroll
            for (int j = 0; j < 2; j++) {
                bf16x8 bv = *(const bf16x8*)&Bs2[wn * 32 + j * 16 + lr][lk * 8];
                acc[j] = __builtin_amdgcn_mfma_f32_16x16x32_bf16(af, bv, acc[j], 0, 0, 0);
            }
        }
#pragma unroll
        for (int j = 0; j < 2; j++)
#pragma unroll
            for (int r = 0; r < 4; r++) {
                float v = acc[j][r];
                res[j][r] += (v > 0.0f ? v : (expf(v) - 1.0f)); // elu
            }
        __syncthreads();
    }
#pragma unroll
    for (int j = 0; j < 2; j++) {
        int n0 = mt * 32 + wm * 16 + lk * 4;
        int og = ot * 64 + wn * 32 + j * 16 + lr;
#pragma unroll
        for (int r = 0; r < 4; r++) {
            size_t idx = (size_t)(b * 256 + n0 + r) * 768 + og;
            float v = 0.5f * res[j][r] + resid[idx];
            xout[idx] = v;
            if (xbout) xbout[idx] = f2bf(v);
        }
    }
}

// ---------------- e2row: one block per (b,n) row, 384 cols ------------------
DEVINL void e2row_body(const float* __restrict__ e, const us* __restrict__ att1b,
                       const us* __restrict__ att2b, const us* __restrict__ Bfrag,
                       float* __restrict__ e2out, int bb, int n) {
    __shared__ us blB[1536 * 8];
    __shared__ float eL[1792];
    __shared__ float aL[4][256]; // 0,1: att1 h; 2,3: att2 h
    const int t = threadIdx.x;
    for (int i = t; i < 1536; i += 256)
        *(bf16x8*)&blB[i * 8] = *(const bf16x8*)&Bfrag[(size_t)i * 8];
    const float* erow = e + (size_t)(bb * 256 + n) * 256 * 7;
#pragma unroll
    for (int i = 0; i < 7; i++) eL[t + i * 256] = erow[t + i * 256];
    const size_t abase = (size_t)bb * 2 * 65536 + n * 256;
    aL[0][t] = bf2f(att1b[abase + t]);
    aL[1][t] = bf2f(att1b[abase + 65536 + t]);
    aL[2][t] = bf2f(att2b[abase + t]);
    aL[3][t] = bf2f(att2b[abase + 65536 + t]);
    __syncthreads();
    const int wv = t >> 6, l = t & 63, le = l & 15, lq = l >> 4;
    const int h1 = lq >> 1, h2 = lq & 1;
    bf16x8 av[4];
#pragma unroll
    for (int g = 0; g < 4; g++) {
        int m = g * 64 + wv * 16 + le;
        float c = aL[h1][m] * aL[2 + h2][m];
        us pk[8];
#pragma unroll
        for (int j = 0; j < 7; j++) pk[j] = f2bf(c * eL[m * 7 + j]);
        pk[7] = 0;
        av[g] = *(bf16x8*)pk;
    }
    const f32x4 zero = {0, 0, 0, 0};
    const size_t rowbase = (size_t)bb * 65536 + n * 256;
#pragma unroll
    for (int cg = 0; cg < 3; cg++) {
        bf16x8 bfr[8];
#pragma unroll
        for (int i = 0; i < 8; i++) bfr[i] = *(const bf16x8*)&blB[(cg * 512 + i * 64 + l) * 8];
        for (int g = 0; g < 4; g++) {
            size_t eidx = rowbase + g * 64 + wv * 16 + le;
#pragma unroll
            for (int i = 0; i < 8; i++) {
                f32x4 acc = __builtin_amdgcn_mfma_f32_16x16x32_bf16(bfr[i], av[g], zero, 0, 0, 0);
                *(f32x4*)&e2out[eidx * 384 + cg * 128 + i * 16 + lq * 4] = acc;
            }
        }
    }
}

// ========================= stage kernels ====================================
__global__ __launch_bounds__(256) void stage1(
    const float* W1, const float* W2, const float* We1, const float* We2,
    const float* a1s, const float* a1d, const float* a1e,
    const float* a2s, const float* a2d,
    const float* x, us* W1T, us* W2T, us* xb,
    float* q, float* u1, float* Mcat) {
    int b = blockIdx.x;
    if (b < 577)       pre_body(W1, W2, We1, We2, a1s, a1d, a1e, a2s, a2d, q, u1, Mcat, b);
    else if (b < 865)  transpose_body(W1, W1T, b - 577);
    else if (b < 1153) transpose_body(W2, W2T, b - 865);
    else               cvt_body(x, xb, b - 1153);
}

__global__ __launch_bounds__(256) void stage2(
    const float* Mcat, const float* a2e, float* wbuf, us* Bfrag,
    const float* x, const float* qs, const float* qd, float* s1s, float* s1d) {
    int b = blockIdx.x;
    if (b < 1)        wcalc_body(Mcat, a2e, wbuf);
    else if (b < 25)  bfrag_body(Mcat, Bfrag, b - 1);
    else { int i = b - 25; sdots_body(x, qs, qd, s1s, s1d, i & 255, i >> 8); }
}

__global__ __launch_bounds__(256) void stage3(
    const float* e, const int* adj, const float* s1s, const float* s1d,
    const float* u1, us* att1b, const us* xb, const us* W1T, us* WhT1) {
    int b = blockIdx.x;
    if (b < 512) att1_body(e, adj, s1s, s1d, u1, att1b, b & 255, b >> 8);
    else { int g = b - 512; gemm_xw_body(xb, W1T, WhT1, g & 7, (g >> 3) % 12, g / 96); }
}

__global__ __launch_bounds__(256) void stage4(
    const us* att1b, const us* WhT1, const float* x, float* x1, us* xb1) {
    int b = blockIdx.x;
    gemm_att_body(att1b, WhT1, x, x1, xb1, b & 7, (b >> 3) % 12, b / 96);
}

__global__ __launch_bounds__(256) void stage5(
    const float* x1, const float* qs, const float* qd, float* s2s, float* s2d,
    const us* xb1, const us* W2T, us* WhT2) {
    int b = blockIdx.x;
    if (b < 512) sdots_body(x1, qs, qd, s2s, s2d, b & 255, b >> 8);
    else { int g = b - 512; gemm_xw_body(xb1, W2T, WhT2, g & 7, (g >> 3) % 12, g / 96); }
}

__global__ __launch_bounds__(256) void stage6(
    const float* e, const int* adj, const float* s2s, const float* s2d,
    const float* wbuf, const us* att1b, us* att2b) {
    int b = blockIdx.x;
    att2_body(e, adj, s2s, s2d, wbuf, att1b, att2b, b & 255, b >> 8);
}

__global__ __launch_bounds__(256) void stage7(
    const us* att2b, const us* WhT2, const float* x, float* x2out,
    const float* e, const us* att1b, const us* Bfrag, float* e2out) {
    int b = blockIdx.x;
    if (b < 192) gemm_att_body(att2b, WhT2, x, x2out, (us*)nullptr, b & 7, (b >> 3) % 12, b / 96);
    else { int r = b - 192; e2row_body(e, att1b, att2b, Bfrag, e2out, r >> 8, r & 255); }
}

// ---------------------------------------------------------------------------
extern "C" void kernel_launch(void* const* d_in, const int* in_sizes, int n_in,
                              void* d_out, int out_size, void* d_ws, size_t ws_size,
                              hipStream_t stream) {
    const float* x   = (const float*)d_in[0];
    const int*   adj = (const int*)d_in[1];
    const float* e   = (const float*)d_in[2];
    const float* W1  = (const float*)d_in[3];
    const float* We1 = (const float*)d_in[4];
    const float* a1s = (const float*)d_in[5];
    const float* a1d = (const float*)d_in[6];
    const float* a1e = (const float*)d_in[7];
    const float* W2  = (const float*)d_in[8];
    const float* We2 = (const float*)d_in[9];
    const float* a2s = (const float*)d_in[10];
    const float* a2d = (const float*)d_in[11];
    const float* a2e = (const float*)d_in[12];

    float* out   = (float*)d_out;
    float* x2out = out;                  // [2][256][768]
    float* e2out = out + 393216;         // [2][256][256][384]

    // all scratch in d_ws (~12.2 MB; ws is ~600 MB per fill-size evidence)
    char* ws = (char*)d_ws;
    float* q     = (float*)(ws + 0);         // [4][2][768]
    float* u1    = (float*)(ws + 24576);     // [2][8]
    float* wbuf  = (float*)(ws + 24640);     // [2][2][8]
    float* Mcat  = (float*)(ws + 24832);     // [32][384]
    us*    Bfrag = (us*)(ws + 73984);        // [24][64][8]
    float* s1s   = (float*)(ws + 98560);
    float* s1d   = (float*)(ws + 102656);
    float* s2s   = (float*)(ws + 106752);
    float* s2d   = (float*)(ws + 110848);
    us*    att1b = (us*)(ws + 114944);       // [2][2][256][256] bf16
    us*    att2b = (us*)(ws + 639232);
    us*    W1T   = (us*)(ws + 1163520);      // [2][768][768] bf16
    us*    W2T   = (us*)(ws + 3522816);
    us*    xb    = (us*)(ws + 5882112);      // [512][768] bf16
    us*    xb1   = (us*)(ws + 6668544);
    us*    WhT1  = (us*)(ws + 7454976);      // [2][2][768][256] bf16
    us*    WhT2  = (us*)(ws + 9027840);
    float* x1    = (float*)(ws + 10600704);  // [512][768] f32

    stage1<<<1345, 256, 0, stream>>>(W1, W2, We1, We2, a1s, a1d, a1e, a2s, a2d,
                                     x, W1T, W2T, xb, q, u1, Mcat);
    stage2<<<537, 256, 0, stream>>>(Mcat, a2e, wbuf, Bfrag, x, q + 0, q + 1536, s1s, s1d);
    stage3<<<704, 256, 0, stream>>>(e, adj, s1s, s1d, u1, att1b, xb, W1T, WhT1);
    stage4<<<192, 256, 0, stream>>>(att1b, WhT1, x, x1, xb1);
    stage5<<<704, 256, 0, stream>>>(x1, q + 3072, q + 4608, s2s, s2d, xb1, W2T, WhT2);
    stage6<<<512, 256, 0, stream>>>(e, adj, s2s, s2d, wbuf, att1b, att2b);
    stage7<<<704, 256, 0, stream>>>(att2b, WhT2, x, x2out, e, att1b, Bfrag, e2out);
}